// Round 5
// baseline (5781.152 us; speedup 1.0000x reference)
//
#include <hip/hip_runtime.h>
#include <cmath>
#include <stdint.h>

#define BB 32
#define TT 24
#define NN 1024
#define FF 2
#define UU 16
#define HH 32
#define TFN 31
#define GRID 256

typedef __attribute__((ext_vector_type(8))) short bf16x8;
typedef __attribute__((ext_vector_type(4))) float f32x4;
typedef unsigned short u16;
typedef unsigned int   u32;

// ---- static device buffers ----
__device__ __align__(16) u16 g_Ab [(size_t)BB*NN*NN];  // bf16 A, row-major [b][i][k]
__device__ __align__(16) u16 g_ru [(size_t)BB*32*NN];  // bf16 [b][j][n] (col-major over n)
__device__ __align__(16) u16 g_cin[(size_t)BB*16*NN];  // bf16 [b][j][n]
__device__ float g_c2[BB*FF];
__device__ unsigned g_count;   // barrier arrive counter (returns to 0 after each run)
__device__ unsigned g_gen;     // barrier generation (monotonic across launches)

__device__ __forceinline__ float sigmf(float x) { return 1.0f/(1.0f+expf(-x)); }
__device__ __forceinline__ u16 f2bf(float f) {
  u32 u = __float_as_uint(f);
  return (u16)((u + 0x7fffu + ((u >> 16) & 1u)) >> 16);
}

// ---- device-scope grid barrier (all 256 blocks guaranteed co-resident) ----
__device__ __forceinline__ void gbar(unsigned &gen) {
  __threadfence();
  __syncthreads();
  if (threadIdx.x == 0) {
    unsigned tgt = gen + 1;
    unsigned v = __hip_atomic_fetch_add(&g_count, 1u, __ATOMIC_ACQ_REL, __HIP_MEMORY_SCOPE_AGENT);
    if (v == GRID-1u) {
      __hip_atomic_store(&g_count, 0u, __ATOMIC_RELAXED, __HIP_MEMORY_SCOPE_AGENT);
      __hip_atomic_store(&g_gen, tgt, __ATOMIC_RELEASE, __HIP_MEMORY_SCOPE_AGENT);
    } else {
      while ((int)(__hip_atomic_load(&g_gen, __ATOMIC_ACQUIRE, __HIP_MEMORY_SCOPE_AGENT) - tgt) < 0)
        __builtin_amdgcn_s_sleep(8);
    }
  }
  __syncthreads();
  gen += 1;
}

// ---------------- convert A fp32 -> bf16 ----------------
__global__ __launch_bounds__(256)
void k_convert(const float* __restrict__ A) {
  size_t idx = ((size_t)blockIdx.x*256 + threadIdx.x)*8;
  float4 v0 = *(const float4*)(A + idx);
  float4 v1 = *(const float4*)(A + idx + 4);
  u32 p0 = (u32)f2bf(v0.x) | ((u32)f2bf(v0.y) << 16);
  u32 p1 = (u32)f2bf(v0.z) | ((u32)f2bf(v0.w) << 16);
  u32 p2 = (u32)f2bf(v1.x) | ((u32)f2bf(v1.y) << 16);
  u32 p3 = (u32)f2bf(v1.z) | ((u32)f2bf(v1.w) << 16);
  *(uint4*)&g_Ab[idx] = make_uint4(p0, p1, p2, p3);
}

// ---------------- LSTM + ff + const2 (tiny) ----------------
__global__ __launch_bounds__(128)
void k_lstm(const float* __restrict__ trend, const float* __restrict__ tfeat,
            const float* __restrict__ Wih0, const float* __restrict__ Whh0,
            const float* __restrict__ bih0, const float* __restrict__ bhh0,
            const float* __restrict__ Wih1, const float* __restrict__ Whh1,
            const float* __restrict__ bih1, const float* __restrict__ bhh1,
            const float* __restrict__ ffW, const float* __restrict__ ffb,
            const float* __restrict__ gcnW) {
  __shared__ float h[HH], c[HH], g[4*HH], hs0[TT][HH], tr[HH], fe[HH];
  int b = blockIdx.x, tid = threadIdx.x;
  if (tid < HH) { h[tid]=0.f; c[tid]=0.f; }
  __syncthreads();
  for (int t=0;t<TT;t++) {
    float x0 = trend[(b*TT+t)*FF+0], x1 = trend[(b*TT+t)*FF+1];
    float gv = bih0[tid] + bhh0[tid] + x0*Wih0[tid*FF+0] + x1*Wih0[tid*FF+1];
#pragma unroll
    for (int k=0;k<HH;k++) gv += h[k]*Whh0[tid*HH+k];
    g[tid] = gv;
    __syncthreads();
    if (tid < HH) {
      float ii = sigmf(g[tid]), ff = sigmf(g[HH+tid]);
      float gg = tanhf(g[2*HH+tid]), oo = sigmf(g[3*HH+tid]);
      float cn = ff*c[tid] + ii*gg;
      c[tid] = cn;
      float hn = oo*tanhf(cn);
      h[tid] = hn;
      hs0[t][tid] = hn;
    }
    __syncthreads();
  }
  if (tid < HH) { h[tid]=0.f; c[tid]=0.f; }
  __syncthreads();
  for (int t=0;t<TT;t++) {
    float gv = bih1[tid] + bhh1[tid];
#pragma unroll
    for (int k=0;k<HH;k++) gv += hs0[t][k]*Wih1[tid*HH+k];
#pragma unroll
    for (int k=0;k<HH;k++) gv += h[k]*Whh1[tid*HH+k];
    g[tid] = gv;
    __syncthreads();
    if (tid < HH) {
      float ii = sigmf(g[tid]), ff = sigmf(g[HH+tid]);
      float gg = tanhf(g[2*HH+tid]), oo = sigmf(g[3*HH+tid]);
      float cn = ff*c[tid] + ii*gg;
      c[tid] = cn;
      h[tid] = oo*tanhf(cn);
    }
    __syncthreads();
  }
  if (tid < HH) {
    tr[tid] = h[tid];
    float fv = ffb[tid];
#pragma unroll
    for (int j=0;j<TFN;j++) fv += tfeat[b*TFN+j]*ffW[tid*TFN+j];
    fe[tid] = fmaxf(fv, 0.f);
  }
  __syncthreads();
  if (tid < FF) {
    float s = 0.f;
#pragma unroll
    for (int j=0;j<HH;j++) s += tr[j]*gcnW[tid*80+16+j];
#pragma unroll
    for (int j=0;j<HH;j++) s += fe[j]*gcnW[tid*80+48+j];
    g_c2[b*FF+tid] = s;
  }
}

// ---- pass helpers: P = A(128 block rows) @ Y^T, A from global regs, Y via LDS ----
__device__ __forceinline__ void pass32(const u16* __restrict__ Ag,
    const u16* __restrict__ Yg, u16 (*S)[32][136], float (*P)[33], int tid) {
  const int w = tid>>6, lane = tid&63, m = lane&15, quad = lane>>4;
  const int jy = tid>>3, py = tid&7;
  const size_t ar0 = (size_t)(w*32 + m)*NN;
  const size_t ar1 = (size_t)(w*32 + 16 + m)*NN;
  bf16x8 a0[4], a1[4], a0n[4], a1n[4];
  uint4 y0, y1;
#pragma unroll
  for (int ss=0;ss<4;ss++) {
    a0[ss] = *(const bf16x8*)&Ag[ar0 + ss*32 + quad*8];
    a1[ss] = *(const bf16x8*)&Ag[ar1 + ss*32 + quad*8];
  }
  y0 = *(const uint4*)&Yg[(size_t)jy*NN + py*16];
  y1 = *(const uint4*)&Yg[(size_t)jy*NN + py*16 + 8];
  *(uint4*)&S[0][jy][py*16]   = y0;
  *(uint4*)&S[0][jy][py*16+8] = y1;
  f32x4 acc00={0,0,0,0}, acc01={0,0,0,0}, acc10={0,0,0,0}, acc11={0,0,0,0};
#pragma unroll
  for (int c=0;c<8;c++) {
    if (c<7) {
      int k0 = (c+1)*128;
#pragma unroll
      for (int ss=0;ss<4;ss++) {
        a0n[ss] = *(const bf16x8*)&Ag[ar0 + k0 + ss*32 + quad*8];
        a1n[ss] = *(const bf16x8*)&Ag[ar1 + k0 + ss*32 + quad*8];
      }
      y0 = *(const uint4*)&Yg[(size_t)jy*NN + k0 + py*16];
      y1 = *(const uint4*)&Yg[(size_t)jy*NN + k0 + py*16 + 8];
    }
    __syncthreads();
#pragma unroll
    for (int ss=0;ss<4;ss++) {
      bf16x8 b0 = *(const bf16x8*)&S[c&1][m]   [ss*32+quad*8];
      bf16x8 b1 = *(const bf16x8*)&S[c&1][16+m][ss*32+quad*8];
      acc00 = __builtin_amdgcn_mfma_f32_16x16x32_bf16(a0[ss], b0, acc00,0,0,0);
      acc01 = __builtin_amdgcn_mfma_f32_16x16x32_bf16(a0[ss], b1, acc01,0,0,0);
      acc10 = __builtin_amdgcn_mfma_f32_16x16x32_bf16(a1[ss], b0, acc10,0,0,0);
      acc11 = __builtin_amdgcn_mfma_f32_16x16x32_bf16(a1[ss], b1, acc11,0,0,0);
    }
    if (c<7) {
      *(uint4*)&S[(c+1)&1][jy][py*16]   = y0;
      *(uint4*)&S[(c+1)&1][jy][py*16+8] = y1;
#pragma unroll
      for (int ss=0;ss<4;ss++) { a0[ss]=a0n[ss]; a1[ss]=a1n[ss]; }
    }
  }
#pragma unroll
  for (int r=0;r<4;r++) {
    P[w*32 + quad*4 + r][m]         = acc00[r];
    P[w*32 + quad*4 + r][16+m]      = acc01[r];
    P[w*32 + 16 + quad*4 + r][m]    = acc10[r];
    P[w*32 + 16 + quad*4 + r][16+m] = acc11[r];
  }
  __syncthreads();
}

__device__ __forceinline__ void pass16(const u16* __restrict__ Ag,
    const u16* __restrict__ Yg, u16 (*S)[32][136], float (*P)[33], int tid) {
  const int w = tid>>6, lane = tid&63, m = lane&15, quad = lane>>4;
  const int jy = tid>>4, py = tid&15;
  const size_t ar0 = (size_t)(w*32 + m)*NN;
  const size_t ar1 = (size_t)(w*32 + 16 + m)*NN;
  bf16x8 a0[4], a1[4], a0n[4], a1n[4];
  uint4 y0;
#pragma unroll
  for (int ss=0;ss<4;ss++) {
    a0[ss] = *(const bf16x8*)&Ag[ar0 + ss*32 + quad*8];
    a1[ss] = *(const bf16x8*)&Ag[ar1 + ss*32 + quad*8];
  }
  y0 = *(const uint4*)&Yg[(size_t)jy*NN + py*8];
  *(uint4*)&S[0][jy][py*8] = y0;
  f32x4 acc0={0,0,0,0}, acc1={0,0,0,0};
#pragma unroll
  for (int c=0;c<8;c++) {
    if (c<7) {
      int k0 = (c+1)*128;
#pragma unroll
      for (int ss=0;ss<4;ss++) {
        a0n[ss] = *(const bf16x8*)&Ag[ar0 + k0 + ss*32 + quad*8];
        a1n[ss] = *(const bf16x8*)&Ag[ar1 + k0 + ss*32 + quad*8];
      }
      y0 = *(const uint4*)&Yg[(size_t)jy*NN + k0 + py*8];
    }
    __syncthreads();
#pragma unroll
    for (int ss=0;ss<4;ss++) {
      bf16x8 b0 = *(const bf16x8*)&S[c&1][m][ss*32+quad*8];
      acc0 = __builtin_amdgcn_mfma_f32_16x16x32_bf16(a0[ss], b0, acc0,0,0,0);
      acc1 = __builtin_amdgcn_mfma_f32_16x16x32_bf16(a1[ss], b0, acc1,0,0,0);
    }
    if (c<7) {
      *(uint4*)&S[(c+1)&1][jy][py*8] = y0;
#pragma unroll
      for (int ss=0;ss<4;ss++) { a0[ss]=a0n[ss]; a1[ss]=a1n[ss]; }
    }
  }
#pragma unroll
  for (int r=0;r<4;r++) {
    P[w*32 + quad*4 + r][m]      = acc0[r];
    P[w*32 + 16 + quad*4 + r][m] = acc1[r];
  }
  __syncthreads();
}

// ---------------- persistent kernel: whole GRU encoder + final GCN ----------------
__global__ __launch_bounds__(256, 2)
void k_persist(const float* __restrict__ recent,
               const float* __restrict__ g1rW, const float* __restrict__ g1rb,
               const float* __restrict__ g1uW, const float* __restrict__ g1ub,
               const float* __restrict__ g1cW, const float* __restrict__ g1cb,
               const float* __restrict__ g2rW, const float* __restrict__ g2rb,
               const float* __restrict__ g2uW, const float* __restrict__ g2ub,
               const float* __restrict__ g2cW, const float* __restrict__ g2cb,
               const float* __restrict__ gcnW, const float* __restrict__ gcnb,
               float* __restrict__ out) {
  __shared__ u16 S[2][32][136];
  __shared__ float P[128][33];
  __shared__ float E1[128][17];
  __shared__ float E2[128][17];
  __shared__ float sW1ru[32*18], sW1c[16*18], sW2ru[32*32], sW2c[16*32];
  __shared__ float sB[6*16], sGw[2*16], sGb[2];

  const int tid = threadIdx.x;
  const int b = blockIdx.x >> 3, seg = blockIdx.x & 7, R0 = seg*128;
  const u16* Ag  = g_Ab + ((size_t)(b*NN + R0))*NN;
  const u16* Yru = g_ru  + ((size_t)b*32 << 10);
  const u16* Yci = g_cin + ((size_t)b*16 << 10);
  const int row = tid >> 1, jj = tid & 1;   // epilogue: 2 threads/row, 8 gates each
  const int n = R0 + row;

  // ---- stage weights into LDS ----
  for (int i=tid; i<32*18; i+=256) sW1ru[i] = (i<288) ? g1rW[i] : g1uW[i-288];
  for (int i=tid; i<16*18; i+=256) sW1c[i]  = g1cW[i];
  for (int i=tid; i<32*32; i+=256) sW2ru[i] = (i<512) ? g2rW[i] : g2uW[i-512];
  for (int i=tid; i<16*32; i+=256) sW2c[i]  = g2cW[i];
  if (tid < 96) sB[tid] = (tid<16)?g1rb[tid] : (tid<32)?g1ub[tid-16] : (tid<48)?g1cb[tid-32]
                        : (tid<64)?g2rb[tid-48] : (tid<80)?g2ub[tid-64] : g2cb[tid-80];
  if (tid < 32) sGw[tid] = gcnW[(tid>>4)*80 + (tid&15)];
  if (tid < 2)  sGb[tid] = gcnb[tid];
  __syncthreads();
  const float *sB1r=sB, *sB1u=sB+16, *sB1c=sB+32, *sB2r=sB+48, *sB2u=sB+64, *sB2c=sB+80;

  unsigned gen = __hip_atomic_load(&g_gen, __ATOMIC_ACQUIRE, __HIP_MEMORY_SCOPE_AGENT);

  float h1r[8], h2r[8], ur[8];
#pragma unroll
  for (int q=0;q<8;q++) { h1r[q]=0.f; h2r[q]=0.f; ur[q]=0.f; }

  // ---- init: ru_in for t=0 (h=0) ----
  {
    const float* xr = recent + ((size_t)(b*TT)*NN + n)*FF;
    float x0 = xr[0], x1 = xr[1];
#pragma unroll
    for (int q2=0;q2<16;q2++) {
      int j2 = jj*16 + q2;
      float s = fmaf(x0, sW1ru[j2*18+0], x1*sW1ru[j2*18+1]);
      g_ru[((size_t)(b*32+j2)<<10) + n] = f2bf(s);
    }
  }
  gbar(gen);

#pragma unroll 1
  for (int t=0; t<TT; t++) {
    // ===== cell 1: ru pass =====
    pass32(Ag, Yru, S, P, tid);
    {
#pragma unroll
      for (int q=0;q<8;q++) {
        int j = jj*8+q;
        float rv = sigmf(P[row][j] + sB1r[j]);
        ur[q]    = sigmf(P[row][16+j] + sB1u[j]);
        E1[row][j] = rv * h1r[q];
      }
      __syncthreads();
      const float* xr = recent + ((size_t)(b*TT + t)*NN + n)*FF;
      float x0 = xr[0], x1 = xr[1];
#pragma unroll
      for (int q2=0;q2<8;q2++) {
        int j = jj*8+q2;
        float s = fmaf(x0, sW1c[j*18+0], x1*sW1c[j*18+1]);
#pragma unroll
        for (int f=0;f<16;f++) s = fmaf(E1[row][f], sW1c[j*18+2+f], s);
        g_cin[((size_t)(b*16+j)<<10) + n] = f2bf(s);
      }
    }
    gbar(gen);

    // ===== cell 1: c pass -> h1 update, ru_in for cell 2 =====
    pass16(Ag, Yci, S, P, tid);
    {
#pragma unroll
      for (int q=0;q<8;q++) {
        int j = jj*8+q;
        float cv = tanhf(P[row][j] + sB1c[j]);
        h1r[q] = ur[q]*h1r[q] + (1.f-ur[q])*cv;
        E1[row][j] = h1r[q];
        E2[row][j] = h2r[q];
      }
      __syncthreads();
#pragma unroll
      for (int q2=0;q2<16;q2++) {
        int j2 = jj*16+q2;
        float s = 0.f;
#pragma unroll
        for (int f=0;f<16;f++) s = fmaf(E1[row][f], sW2ru[j2*32+f], s);
#pragma unroll
        for (int f=0;f<16;f++) s = fmaf(E2[row][f], sW2ru[j2*32+16+f], s);
        g_ru[((size_t)(b*32+j2)<<10) + n] = f2bf(s);
      }
    }
    gbar(gen);

    // ===== cell 2: ru pass =====
    pass32(Ag, Yru, S, P, tid);
    {
#pragma unroll
      for (int q=0;q<8;q++) {
        int j = jj*8+q;
        float rv = sigmf(P[row][j] + sB2r[j]);
        ur[q]    = sigmf(P[row][16+j] + sB2u[j]);
        E1[row][j] = rv * h2r[q];
        E2[row][j] = h1r[q];            // x for cell 2 = h1_new
      }
      __syncthreads();
#pragma unroll
      for (int q2=0;q2<8;q2++) {
        int j = jj*8+q2;
        float s = 0.f;
#pragma unroll
        for (int f=0;f<16;f++) s = fmaf(E2[row][f], sW2c[j*32+f], s);
#pragma unroll
        for (int f=0;f<16;f++) s = fmaf(E1[row][f], sW2c[j*32+16+f], s);
        g_cin[((size_t)(b*16+j)<<10) + n] = f2bf(s);
      }
    }
    gbar(gen);

    // ===== cell 2: c pass -> h2 update, next input =====
    pass16(Ag, Yci, S, P, tid);
    {
#pragma unroll
      for (int q=0;q<8;q++) {
        int j = jj*8+q;
        float cv = tanhf(P[row][j] + sB2c[j]);
        h2r[q] = ur[q]*h2r[q] + (1.f-ur[q])*cv;
      }
      if (t < TT-1) {
#pragma unroll
        for (int q=0;q<8;q++) E1[row][jj*8+q] = h1r[q];
        __syncthreads();
        const float* xr = recent + ((size_t)(b*TT + t + 1)*NN + n)*FF;
        float x0 = xr[0], x1 = xr[1];
#pragma unroll
        for (int q2=0;q2<16;q2++) {
          int j2 = jj*16+q2;
          float s = fmaf(x0, sW1ru[j2*18+0], x1*sW1ru[j2*18+1]);
#pragma unroll
          for (int f=0;f<16;f++) s = fmaf(E1[row][f], sW1ru[j2*18+2+f], s);
          g_ru[((size_t)(b*32+j2)<<10) + n] = f2bf(s);
        }
      } else {
#pragma unroll
        for (int q=0;q<8;q++) E1[row][jj*8+q] = h2r[q];
        __syncthreads();
#pragma unroll
        for (int q2=0;q2<8;q2++) {
          int j = jj*8+q2;
          float s = 0.f;
          if (j < FF) {
            s = g_c2[b*FF + j];
#pragma unroll
            for (int f=0;f<16;f++) s = fmaf(E1[row][f], sGw[j*16+f], s);
          }
          g_cin[((size_t)(b*16+j)<<10) + n] = f2bf(s);
        }
      }
    }
    gbar(gen);
  }

  // ===== final: out = tanh(A @ small_in + b) =====
  pass16(Ag, Yci, S, P, tid);
  if (jj == 0) {
    float2 o = make_float2(tanhf(P[row][0] + sGb[0]), tanhf(P[row][1] + sGb[1]));
    *(float2*)&out[((size_t)(b<<10) + n)*FF] = o;
  }
}

extern "C" void kernel_launch(void* const* d_in, const int* in_sizes, int n_in,
                              void* d_out, int out_size, void* d_ws, size_t ws_size,
                              hipStream_t stream) {
  (void)in_sizes; (void)n_in; (void)d_ws; (void)ws_size; (void)out_size;
  const float* recent = (const float*)d_in[0];
  const float* trend  = (const float*)d_in[1];
  const float* A      = (const float*)d_in[2];
  const float* tfeat  = (const float*)d_in[3];
  const float* g1rW = (const float*)d_in[4];  const float* g1rb = (const float*)d_in[5];
  const float* g1uW = (const float*)d_in[6];  const float* g1ub = (const float*)d_in[7];
  const float* g1cW = (const float*)d_in[8];  const float* g1cb = (const float*)d_in[9];
  const float* g2rW = (const float*)d_in[10]; const float* g2rb = (const float*)d_in[11];
  const float* g2uW = (const float*)d_in[12]; const float* g2ub = (const float*)d_in[13];
  const float* g2cW = (const float*)d_in[14]; const float* g2cb = (const float*)d_in[15];
  const float* Wih0 = (const float*)d_in[16]; const float* Whh0 = (const float*)d_in[17];
  const float* bih0 = (const float*)d_in[18]; const float* bhh0 = (const float*)d_in[19];
  const float* Wih1 = (const float*)d_in[20]; const float* Whh1 = (const float*)d_in[21];
  const float* bih1 = (const float*)d_in[22]; const float* bhh1 = (const float*)d_in[23];
  const float* ffW  = (const float*)d_in[24]; const float* ffb  = (const float*)d_in[25];
  const float* gcnW = (const float*)d_in[26]; const float* gcnb = (const float*)d_in[27];
  float* out = (float*)d_out;

  k_convert<<<16384, 256, 0, stream>>>(A);
  k_lstm<<<BB, 128, 0, stream>>>(trend, tfeat, Wih0, Whh0, bih0, bhh0,
                                 Wih1, Whh1, bih1, bhh1, ffW, ffb, gcnW);
  k_persist<<<GRID, 256, 0, stream>>>(recent,
      g1rW, g1rb, g1uW, g1ub, g1cW, g1cb,
      g2rW, g2rb, g2uW, g2ub, g2cW, g2cb,
      gcnW, gcnb, out);
}

// Round 6
// 2564.053 us; speedup vs baseline: 2.2547x; 2.2547x over previous
//
#include <hip/hip_runtime.h>
#include <cmath>
#include <stdint.h>

#define BB 32
#define TT 24
#define NN 1024
#define FF 2
#define UU 16
#define HH 32
#define TFN 31

typedef __attribute__((ext_vector_type(8))) short bf16x8;
typedef __attribute__((ext_vector_type(4))) float f32x4;
typedef unsigned short u16;
typedef unsigned int   u32;

// ---- static device buffers (fully rewritten every call) ----
__device__ __align__(16) u16 g_Ab [(size_t)BB*NN*NN];  // bf16 A, row-major [b][i][k]
__device__ __align__(16) u16 g_ru [(size_t)BB*32*NN];  // bf16 [b][j][n]
__device__ __align__(16) u16 g_cin[(size_t)BB*16*NN];  // bf16 [b][j][n]
__device__ float g_h1[BB*NN*UU];
__device__ float g_h2[BB*NN*UU];
__device__ float g_u [BB*NN*UU];
__device__ float g_c2[BB*FF];

__device__ __forceinline__ float sigmf(float x) { return 1.0f/(1.0f+expf(-x)); }
__device__ __forceinline__ u16 f2bf(float f) {      // RNE fp32 -> bf16
  u32 u = __float_as_uint(f);
  return (u16)((u + 0x7fffu + ((u >> 16) & 1u)) >> 16);
}

// ---------------- convert A fp32 -> bf16 ----------------
__global__ __launch_bounds__(256)
void k_convert(const float* __restrict__ A) {
  size_t idx = ((size_t)blockIdx.x*256 + threadIdx.x)*8;
  float4 v0 = *(const float4*)(A + idx);
  float4 v1 = *(const float4*)(A + idx + 4);
  u32 p0 = (u32)f2bf(v0.x) | ((u32)f2bf(v0.y) << 16);
  u32 p1 = (u32)f2bf(v0.z) | ((u32)f2bf(v0.w) << 16);
  u32 p2 = (u32)f2bf(v1.x) | ((u32)f2bf(v1.y) << 16);
  u32 p3 = (u32)f2bf(v1.z) | ((u32)f2bf(v1.w) << 16);
  *(uint4*)&g_Ab[idx] = make_uint4(p0, p1, p2, p3);
}

// ---------------- init: zero h1/h2, ru_in for step 0 ----------------
__global__ __launch_bounds__(256)
void k_init(const float* __restrict__ recent,
            const float* __restrict__ rW1, const float* __restrict__ uW1) {
  int idx = blockIdx.x*256 + threadIdx.x;
  if (idx >= BB*NN) return;
  int b = idx >> 10, n = idx & (NN-1);
  float x0 = recent[((size_t)(b*TT)*NN + n)*FF + 0];
  float x1 = recent[((size_t)(b*TT)*NN + n)*FF + 1];
#pragma unroll
  for (int j=0;j<16;j++)
    g_ru[(((size_t)b*32 + j)<<10) + n]      = f2bf(x0*rW1[j*18+0] + x1*rW1[j*18+1]);
#pragma unroll
  for (int j=0;j<16;j++)
    g_ru[(((size_t)b*32 + 16 + j)<<10) + n] = f2bf(x0*uW1[j*18+0] + x1*uW1[j*18+1]);
  float* h1 = g_h1 + (size_t)idx*16;
  float* h2 = g_h2 + (size_t)idx*16;
#pragma unroll
  for (int j=0;j<16;j++) { h1[j]=0.f; h2[j]=0.f; }
}

// ---------------- LSTM + ff + const2 (tiny) ----------------
__global__ __launch_bounds__(128)
void k_lstm(const float* __restrict__ trend, const float* __restrict__ tfeat,
            const float* __restrict__ Wih0, const float* __restrict__ Whh0,
            const float* __restrict__ bih0, const float* __restrict__ bhh0,
            const float* __restrict__ Wih1, const float* __restrict__ Whh1,
            const float* __restrict__ bih1, const float* __restrict__ bhh1,
            const float* __restrict__ ffW, const float* __restrict__ ffb,
            const float* __restrict__ gcnW) {
  __shared__ float h[HH], c[HH], g[4*HH], hs0[TT][HH], tr[HH], fe[HH];
  int b = blockIdx.x, tid = threadIdx.x;
  if (tid < HH) { h[tid]=0.f; c[tid]=0.f; }
  __syncthreads();
  for (int t=0;t<TT;t++) {
    float x0 = trend[(b*TT+t)*FF+0], x1 = trend[(b*TT+t)*FF+1];
    float gv = bih0[tid] + bhh0[tid] + x0*Wih0[tid*FF+0] + x1*Wih0[tid*FF+1];
#pragma unroll
    for (int k=0;k<HH;k++) gv += h[k]*Whh0[tid*HH+k];
    g[tid] = gv;
    __syncthreads();
    if (tid < HH) {
      float ii = sigmf(g[tid]), ff = sigmf(g[HH+tid]);
      float gg = tanhf(g[2*HH+tid]), oo = sigmf(g[3*HH+tid]);
      float cn = ff*c[tid] + ii*gg;
      c[tid] = cn;
      float hn = oo*tanhf(cn);
      h[tid] = hn;
      hs0[t][tid] = hn;
    }
    __syncthreads();
  }
  if (tid < HH) { h[tid]=0.f; c[tid]=0.f; }
  __syncthreads();
  for (int t=0;t<TT;t++) {
    float gv = bih1[tid] + bhh1[tid];
#pragma unroll
    for (int k=0;k<HH;k++) gv += hs0[t][k]*Wih1[tid*HH+k];
#pragma unroll
    for (int k=0;k<HH;k++) gv += h[k]*Whh1[tid*HH+k];
    g[tid] = gv;
    __syncthreads();
    if (tid < HH) {
      float ii = sigmf(g[tid]), ff = sigmf(g[HH+tid]);
      float gg = tanhf(g[2*HH+tid]), oo = sigmf(g[3*HH+tid]);
      float cn = ff*c[tid] + ii*gg;
      c[tid] = cn;
      h[tid] = oo*tanhf(cn);
    }
    __syncthreads();
  }
  if (tid < HH) {
    tr[tid] = h[tid];
    float fv = ffb[tid];
#pragma unroll
    for (int j=0;j<TFN;j++) fv += tfeat[b*TFN+j]*ffW[tid*TFN+j];
    fe[tid] = fmaxf(fv, 0.f);
  }
  __syncthreads();
  if (tid < FF) {
    float s = 0.f;
#pragma unroll
    for (int j=0;j<HH;j++) s += tr[j]*gcnW[tid*80+16+j];
#pragma unroll
    for (int j=0;j<HH;j++) s += fe[j]*gcnW[tid*80+48+j];
    g_c2[b*FF+tid] = s;
  }
}

// ------------- MFMA width-32 pass, 256 thr, 32-row tile, 2-way K-split -------------
template<int FX, int CELL>
__global__ __launch_bounds__(256)
void k_mm32(const float* __restrict__ xp,
            const float* __restrict__ rb, const float* __restrict__ ub,
            const float* __restrict__ cW) {
  __shared__ u16 As[32][136];
  __shared__ u16 Ys[32][136];
  __shared__ float P2[2][32][33];
  __shared__ float RH[32][17];
  const int b = blockIdx.y, i0 = blockIdx.x*32, tid = threadIdx.x;
  const int w = tid >> 6, lane = tid & 63, m = lane & 15, quad = lane >> 4;
  const int rg = w & 1, kh = w >> 1;
  const int srow = tid >> 3, sc = tid & 7;
  const u16* Ag = g_Ab + ((size_t)(b*NN + i0))*NN;
  const u16* Yg = g_ru + ((size_t)b*32 << 10);
  f32x4 acc0 = {0,0,0,0}, acc1 = {0,0,0,0};

  for (int k0=0;k0<NN;k0+=128) {
    __syncthreads();
#pragma unroll
    for (int q=0;q<2;q++)
      *(uint4*)&As[srow][sc*8+q*64] = *(const uint4*)&Ag[(size_t)srow*NN + k0 + sc*8 + q*64];
#pragma unroll
    for (int q=0;q<2;q++)
      *(uint4*)&Ys[srow][sc*8+q*64] = *(const uint4*)&Yg[(size_t)srow*NN + k0 + sc*8 + q*64];
    __syncthreads();
#pragma unroll
    for (int s=0;s<2;s++) {
      int ks = kh*2 + s;
      bf16x8 af = *(const bf16x8*)&As[rg*16+m][ks*32+quad*8];
      bf16x8 b0 = *(const bf16x8*)&Ys[m]      [ks*32+quad*8];
      bf16x8 b1 = *(const bf16x8*)&Ys[16+m]   [ks*32+quad*8];
      acc0 = __builtin_amdgcn_mfma_f32_16x16x32_bf16(af, b0, acc0, 0, 0, 0);
      acc1 = __builtin_amdgcn_mfma_f32_16x16x32_bf16(af, b1, acc1, 0, 0, 0);
    }
  }
  __syncthreads();
#pragma unroll
  for (int r=0;r<4;r++) {
    P2[kh][rg*16 + quad*4 + r][m]      = acc0[r];
    P2[kh][rg*16 + quad*4 + r][16 + m] = acc1[r];
  }
  __syncthreads();
  // epilogue: 8 threads/row, 2 gate-indices each
  const int row = tid >> 3, jr = tid & 7, n = i0 + row, bn = b*NN + n;
  {
    const float* hb = (CELL==1) ? &g_h1[(size_t)bn*16] : &g_h2[(size_t)bn*16];
#pragma unroll
    for (int q=0;q<2;q++) {
      int j = jr*2+q;
      float pr = P2[0][row][j]    + P2[1][row][j];
      float pu = P2[0][row][16+j] + P2[1][row][16+j];
      float rv = sigmf(pr + rb[j]);
      g_u[(size_t)bn*16 + j] = sigmf(pu + ub[j]);
      RH[row][j] = rv * hb[j];
    }
  }
  __syncthreads();
  {
    const float* xr = (CELL==1) ? (xp + (size_t)b*TT*NN*FF + (size_t)n*FF)
                                : &g_h1[(size_t)bn*16];
    float xv[FX];
#pragma unroll
    for (int f=0;f<FX;f++) xv[f] = xr[f];
    const int INS = FX + 16;
#pragma unroll
    for (int q=0;q<2;q++) {
      int j = jr*2+q;
      float s = 0.f;
#pragma unroll
      for (int f=0;f<FX;f++) s = fmaf(xv[f], cW[j*INS+f], s);
#pragma unroll
      for (int f=0;f<16;f++) s = fmaf(RH[row][f], cW[j*INS+FX+f], s);
      g_cin[(((size_t)b*16 + j)<<10) + n] = f2bf(s);
    }
  }
}

// ------------- MFMA width-16 pass, 256 thr, 32-row tile, 2-way K-split -------------
// MODE 0: h1 update + ru_in(cell2). MODE 1: h2 update + ru_in(t+1).
// MODE 2: h2 update + small_in. MODE 3: out = tanh(P[:,0:2]+b).
template<int MODE>
__global__ __launch_bounds__(256)
void k_mm16(const float* __restrict__ cb,
            const float* __restrict__ rWn, const float* __restrict__ uWn,
            const float* __restrict__ xnext, const float* __restrict__ gcnW,
            const float* __restrict__ gcnb, float* __restrict__ out) {
  __shared__ u16 As[32][136];
  __shared__ u16 Ys[16][136];
  __shared__ float P2[2][32][17];
  __shared__ float E1[32][17];
  __shared__ float E2[32][17];
  const int b = blockIdx.y, i0 = blockIdx.x*32, tid = threadIdx.x;
  const int w = tid >> 6, lane = tid & 63, m = lane & 15, quad = lane >> 4;
  const int rg = w & 1, kh = w >> 1;
  const int srow = tid >> 3, sc = tid & 7;
  const int yrow = tid >> 4, yc = tid & 15;
  const u16* Ag = g_Ab + ((size_t)(b*NN + i0))*NN;
  const u16* Yg = g_cin + ((size_t)b*16 << 10);
  f32x4 acc0 = {0,0,0,0};

  for (int k0=0;k0<NN;k0+=128) {
    __syncthreads();
#pragma unroll
    for (int q=0;q<2;q++)
      *(uint4*)&As[srow][sc*8+q*64] = *(const uint4*)&Ag[(size_t)srow*NN + k0 + sc*8 + q*64];
    *(uint4*)&Ys[yrow][yc*8] = *(const uint4*)&Yg[(size_t)yrow*NN + k0 + yc*8];
    __syncthreads();
#pragma unroll
    for (int s=0;s<2;s++) {
      int ks = kh*2 + s;
      bf16x8 af = *(const bf16x8*)&As[rg*16+m][ks*32+quad*8];
      bf16x8 bf = *(const bf16x8*)&Ys[m]      [ks*32+quad*8];
      acc0 = __builtin_amdgcn_mfma_f32_16x16x32_bf16(af, bf, acc0, 0, 0, 0);
    }
  }
  __syncthreads();
#pragma unroll
  for (int r=0;r<4;r++) P2[kh][rg*16 + quad*4 + r][m] = acc0[r];
  __syncthreads();

  const int row = tid >> 3, jr = tid & 7, n = i0 + row, bn = b*NN + n;
  if (MODE == 3) {
    if (jr == 0) {
      float p0 = P2[0][row][0] + P2[1][row][0];
      float p1 = P2[0][row][1] + P2[1][row][1];
      float2 o = make_float2(tanhf(p0 + gcnb[0]), tanhf(p1 + gcnb[1]));
      *(float2*)&out[((size_t)b*NN + n)*FF] = o;
    }
    return;
  }
  float* hb = (MODE==0) ? &g_h1[(size_t)bn*16] : &g_h2[(size_t)bn*16];
  const float* ob = (MODE==0) ? &g_h2[(size_t)bn*16] : &g_h1[(size_t)bn*16];
  {
#pragma unroll
    for (int q=0;q<2;q++) {
      int j = jr*2+q;
      float p = P2[0][row][j] + P2[1][row][j];
      float cv = tanhf(p + cb[j]);
      float uv = g_u[(size_t)bn*16 + j];
      float hn = uv*hb[j] + (1.f-uv)*cv;
      hb[j] = hn;
      E1[row][j] = hn;
      if (MODE != 2) E2[row][j] = ob[j];
    }
  }
  __syncthreads();
  if (MODE == 0) {
#pragma unroll
    for (int q2=0;q2<4;q2++) {
      int j2 = jr*4 + q2;
      const float* W = (j2<16) ? (rWn + j2*32) : (uWn + (j2-16)*32);
      float s = 0.f;
#pragma unroll
      for (int f=0;f<16;f++) s = fmaf(E1[row][f], W[f], s);
#pragma unroll
      for (int f=0;f<16;f++) s = fmaf(E2[row][f], W[16+f], s);
      g_ru[(((size_t)b*32 + j2)<<10) + n] = f2bf(s);
    }
  } else if (MODE == 1) {
    const float* xr = xnext + (size_t)b*TT*NN*FF + (size_t)n*FF;
    float x0 = xr[0], x1 = xr[1];
#pragma unroll
    for (int q2=0;q2<4;q2++) {
      int j2 = jr*4 + q2;
      const float* W = (j2<16) ? (rWn + j2*18) : (uWn + (j2-16)*18);
      float s = fmaf(x0, W[0], x1*W[1]);
#pragma unroll
      for (int f=0;f<16;f++) s = fmaf(E2[row][f], W[2+f], s);
      g_ru[(((size_t)b*32 + j2)<<10) + n] = f2bf(s);
    }
  } else {  // MODE 2: small_in rows 0,1 real, 2..15 zero
#pragma unroll
    for (int q=0;q<2;q++) {
      int jl = jr*2+q;
      float s = 0.f;
      if (jl < FF) {
        s = g_c2[b*FF + jl];
#pragma unroll
        for (int f=0;f<16;f++) s = fmaf(E1[row][f], gcnW[jl*80+f], s);
      }
      g_cin[(((size_t)b*16 + jl)<<10) + n] = f2bf(s);
    }
  }
}

extern "C" void kernel_launch(void* const* d_in, const int* in_sizes, int n_in,
                              void* d_out, int out_size, void* d_ws, size_t ws_size,
                              hipStream_t stream) {
  (void)in_sizes; (void)n_in; (void)d_ws; (void)ws_size; (void)out_size;
  const float* recent = (const float*)d_in[0];
  const float* trend  = (const float*)d_in[1];
  const float* A      = (const float*)d_in[2];
  const float* tfeat  = (const float*)d_in[3];
  const float* g1rW = (const float*)d_in[4];  const float* g1rb = (const float*)d_in[5];
  const float* g1uW = (const float*)d_in[6];  const float* g1ub = (const float*)d_in[7];
  const float* g1cW = (const float*)d_in[8];  const float* g1cb = (const float*)d_in[9];
  const float* g2rW = (const float*)d_in[10]; const float* g2rb = (const float*)d_in[11];
  const float* g2uW = (const float*)d_in[12]; const float* g2ub = (const float*)d_in[13];
  const float* g2cW = (const float*)d_in[14]; const float* g2cb = (const float*)d_in[15];
  const float* Wih0 = (const float*)d_in[16]; const float* Whh0 = (const float*)d_in[17];
  const float* bih0 = (const float*)d_in[18]; const float* bhh0 = (const float*)d_in[19];
  const float* Wih1 = (const float*)d_in[20]; const float* Whh1 = (const float*)d_in[21];
  const float* bih1 = (const float*)d_in[22]; const float* bhh1 = (const float*)d_in[23];
  const float* ffW  = (const float*)d_in[24]; const float* ffb  = (const float*)d_in[25];
  const float* gcnW = (const float*)d_in[26]; const float* gcnb = (const float*)d_in[27];
  float* out = (float*)d_out;

  k_convert<<<16384, 256, 0, stream>>>(A);
  k_lstm<<<BB, 128, 0, stream>>>(trend, tfeat, Wih0, Whh0, bih0, bhh0,
                                 Wih1, Whh1, bih1, bhh1, ffW, ffb, gcnW);
  k_init<<<(BB*NN)/256, 256, 0, stream>>>(recent, g1rW, g1uW);

  for (int t=0; t<TT; t++) {
    k_mm32<2,1><<<dim3(32,BB), 256, 0, stream>>>(recent + (size_t)t*NN*FF, g1rb, g1ub, g1cW);
    k_mm16<0><<<dim3(32,BB), 256, 0, stream>>>(g1cb, g2rW, g2uW, nullptr, nullptr, nullptr, nullptr);
    k_mm32<16,2><<<dim3(32,BB), 256, 0, stream>>>(nullptr, g2rb, g2ub, g2cW);
    if (t < TT-1)
      k_mm16<1><<<dim3(32,BB), 256, 0, stream>>>(g2cb, g1rW, g1uW, recent + (size_t)(t+1)*NN*FF, nullptr, nullptr, nullptr);
    else
      k_mm16<2><<<dim3(32,BB), 256, 0, stream>>>(g2cb, nullptr, nullptr, nullptr, gcnW, nullptr, nullptr);
  }
  k_mm16<3><<<dim3(32,BB), 256, 0, stream>>>(nullptr, nullptr, nullptr, nullptr, nullptr, gcnb, out);
}